// Round 19
// baseline (137.827 us; speedup 1.0000x reference)
//
#include <hip/hip_runtime.h>

#define IN_CH   128
#define HIDDEN  256
#define N_GRAPHS 64
#define GN 64      // nodes per gemm block
#define NPB 64     // nodes per bucket
#define LOGNPB 6
#define MAXBUCK 1024
#define NBLK 400   // edge-processing blocks

typedef short short8 __attribute__((ext_vector_type(8)));
typedef float f32x4 __attribute__((ext_vector_type(4)));

__device__ inline unsigned f2bf(float f) {
  unsigned u = __float_as_uint(f);
  return (u + 0x7fffu + ((u >> 16) & 1u)) >> 16;
}
__device__ inline unsigned pack2(float lo, float hi) {
  return (f2bf(hi) << 16) | f2bf(lo);
}
__device__ inline void acc8(uint4 v, float w, float* A) {
  A[0] += w * __uint_as_float(v.x << 16);
  A[1] += w * __uint_as_float(v.x & 0xffff0000u);
  A[2] += w * __uint_as_float(v.y << 16);
  A[3] += w * __uint_as_float(v.y & 0xffff0000u);
  A[4] += w * __uint_as_float(v.z << 16);
  A[5] += w * __uint_as_float(v.z & 0xffff0000u);
  A[6] += w * __uint_as_float(v.w << 16);
  A[7] += w * __uint_as_float(v.w & 0xffff0000u);
}

// P1: x->bf16 + w1->bf16^T casts (grid-stride) + pooled zero-init +
// per-block LDS bucket histogram (stored transposed for P2a coalescing).
__global__ __launch_bounds__(256) void k_p1(
    const float* __restrict__ x, ushort* __restrict__ xh,
    const float* __restrict__ w1, ushort* __restrict__ w1t,
    const int* __restrict__ dst, int* __restrict__ ghist,
    float* __restrict__ pooled, int total8, int e, int nbuck, int chunk) {
  __shared__ int h[MAXBUCK];
  int t = threadIdx.x, b = blockIdx.x;
  for (int k = t; k < nbuck; k += 256) h[k] = 0;
  int gid = b * 256 + t;
  const int nthr = NBLK * 256;
  for (int i = gid; i < total8; i += nthr) {
    const float4* xp = reinterpret_cast<const float4*>(x) + (size_t)i * 2;
    float4 a = xp[0], bb = xp[1];
    uint4 o;
    o.x = pack2(a.x, a.y);
    o.y = pack2(a.z, a.w);
    o.z = pack2(bb.x, bb.y);
    o.w = pack2(bb.z, bb.w);
    reinterpret_cast<uint4*>(xh)[i] = o;
  }
  if (gid < HIDDEN * IN_CH) {
    int nn = gid >> 7, k = gid & 127;
    w1t[gid] = (ushort)f2bf(w1[k * 256 + nn]);
  }
  if (gid < N_GRAPHS * HIDDEN) pooled[gid] = 0.f;
  __syncthreads();
  int s = b * chunk, eend = min(e, s + chunk);
  for (int i = s + t; i < eend; i += 256) atomicAdd(&h[dst[i] >> LOGNPB], 1);
  __syncthreads();
  for (int k = t; k < nbuck; k += 256) ghist[k * NBLK + b] = h[k];  // transposed
}

// P2a: per-bucket exclusive scan over the NBLK blocks (coalesced row read).
__global__ __launch_bounds__(512) void k_p2a(const int* __restrict__ ghist,
    int* __restrict__ boff, int* __restrict__ total, int nbuck) {
  __shared__ int sm[512];
  int k = blockIdx.x, t = threadIdx.x;
  int v = (t < NBLK) ? ghist[k * NBLK + t] : 0;
  sm[t] = v;
  __syncthreads();
  for (int d = 1; d < 512; d <<= 1) {
    int add = (t >= d) ? sm[t - d] : 0;
    __syncthreads();
    sm[t] += add;
    __syncthreads();
  }
  if (t < NBLK) boff[k * NBLK + t] = sm[t] - v;
  if (t == 511) total[k] = sm[511];
}

// P3: scatter edges into bucket-contiguous ebuf via LDS cursors.
// Computes the bucket-total exclusive scan (tbase) in-block.
// ebuf entry: src (low 16b, N<65536) | dst-within-bucket (bits 16..21).
__global__ __launch_bounds__(256) void k_p3(
    const int* __restrict__ src, const int* __restrict__ dst,
    const int* __restrict__ boff, const int* __restrict__ total,
    int* __restrict__ ebuf, int e, int nbuck, int chunk) {
  __shared__ int cur[MAXBUCK];
  __shared__ int ts[256];
  int t = threadIdx.x, b = blockIdx.x;
  int t4 = t * 4;
  int v0 = (t4 + 0 < nbuck) ? total[t4 + 0] : 0;
  int v1 = (t4 + 1 < nbuck) ? total[t4 + 1] : 0;
  int v2 = (t4 + 2 < nbuck) ? total[t4 + 2] : 0;
  int v3 = (t4 + 3 < nbuck) ? total[t4 + 3] : 0;
  int lsum = v0 + v1 + v2 + v3;
  ts[t] = lsum;
  __syncthreads();
  for (int d = 1; d < 256; d <<= 1) {
    int add = (t >= d) ? ts[t - d] : 0;
    __syncthreads();
    ts[t] += add;
    __syncthreads();
  }
  int base = ts[t] - lsum;
  cur[t4 + 0] = base;
  cur[t4 + 1] = base + v0;
  cur[t4 + 2] = base + v0 + v1;
  cur[t4 + 3] = base + v0 + v1 + v2;
  __syncthreads();
  for (int k = t; k < nbuck; k += 256) cur[k] += boff[k * NBLK + b];
  __syncthreads();
  int s = b * chunk, eend = min(e, s + chunk);
  for (int i = s + t; i < eend; i += 256) {
    int d = dst[i];
    int pos = atomicAdd(&cur[d >> LOGNPB], 1);
    ebuf[pos] = (src[i] & 0xffff) | ((d & (NPB - 1)) << 16);
  }
}

// P4: per-bucket CSR finalize. Computes own tbase via strided sum.
// LDS deg-count + scan + cursor scatter; writes offs (N+1) + dinv; csr = ushort.
__global__ __launch_bounds__(256) void k_p4(const int* __restrict__ ebuf,
    const int* __restrict__ total, ushort* __restrict__ csr, int* __restrict__ offs,
    float* __restrict__ dinv, int n, int nbuck, int etot) {
  __shared__ int dcnt[NPB];
  __shared__ int doff[NPB];
  __shared__ int dcur[NPB];
  __shared__ int red[256];
  int k = blockIdx.x, t = threadIdx.x;
  int partial = 0;
  for (int i = t; i < k; i += 256) partial += total[i];
  red[t] = partial;
  if (t < NPB) dcnt[t] = 0;
  __syncthreads();
  for (int d = 128; d > 0; d >>= 1) {
    if (t < d) red[t] += red[t + d];
    __syncthreads();
  }
  int s = red[0];
  int eend = s + total[k];
  for (int i = s + t; i < eend; i += 256)
    atomicAdd(&dcnt[(ebuf[i] >> 16) & (NPB - 1)], 1);
  __syncthreads();
  if (t < NPB) doff[t] = dcnt[t];
  __syncthreads();
  for (int d = 1; d < NPB; d <<= 1) {
    int add = 0;
    if (t < NPB && t >= d) add = doff[t - d];
    __syncthreads();
    if (t < NPB) doff[t] += add;
    __syncthreads();
  }
  if (t < NPB) {
    int ex = doff[t] - dcnt[t];  // exclusive
    dcur[t] = s + ex;
    int node = k * NPB + t;
    if (node < n) {
      offs[node] = s + ex;
      dinv[node] = 1.0f / sqrtf((float)(dcnt[t] + 1));
    }
  }
  if (k == nbuck - 1 && t == 0) offs[n] = etot;
  __syncthreads();
  for (int i = s + t; i < eend; i += 256) {
    int v = ebuf[i];
    int pos = atomicAdd(&dcur[(v >> 16) & (NPB - 1)], 1);
    csr[pos] = (ushort)v;
  }
}

// 16 nodes/block (1024 threads, fewer blocks -> less dispatch ramp).
// lane = es*16+cg; 6 masked slots/iter -> up to 24 gather rows in flight,
// zero junk traffic (exec-masked loads fetch nothing for ii >= c).
__global__ __launch_bounds__(1024) void k_agg(const ushort* __restrict__ xh,
    const ushort* __restrict__ csr, const int* __restrict__ offs,
    const float* __restrict__ dinv, ushort* __restrict__ yh, int n) {
  int node = blockIdx.x * 16 + (threadIdx.x >> 6);
  if (node >= n) return;
  int lane = threadIdx.x & 63;
  int es = lane >> 4;
  int cg = lane & 15;
  int o = offs[node];
  int c = offs[node + 1] - o;
  // hoist self row (all lanes; 4x duplicate hits L1) so it overlaps the loop
  uint4 xs = *reinterpret_cast<const uint4*>(&xh[(size_t)node * IN_CH + cg * 8]);
  float A[8] = {0.f, 0.f, 0.f, 0.f, 0.f, 0.f, 0.f, 0.f};
  for (int it = 0; it < c; it += 24) {
    float w[6];
    uint4 v[6];
#pragma unroll
    for (int u = 0; u < 6; ++u) {
      int ii = it + u * 4 + es;
      w[u] = 0.f;
      v[u] = make_uint4(0u, 0u, 0u, 0u);
      if (ii < c) {
        int s = (int)csr[o + ii];
        w[u] = dinv[s];
        v[u] = *reinterpret_cast<const uint4*>(&xh[(size_t)s * IN_CH + cg * 8]);
      }
    }
#pragma unroll
    for (int u = 0; u < 6; ++u) acc8(v[u], w[u], A);
  }
#pragma unroll
  for (int k = 0; k < 8; ++k) {
    A[k] += __shfl_xor(A[k], 16, 64);
    A[k] += __shfl_xor(A[k], 32, 64);
  }
  if (es == 0) {
    float dn = dinv[node];
    float xv[8] = {0.f, 0.f, 0.f, 0.f, 0.f, 0.f, 0.f, 0.f};
    acc8(xs, dn, xv);
    float v[8];
#pragma unroll
    for (int k = 0; k < 8; ++k) v[k] = (A[k] + xv[k]) * dn;
    uint4 w;
    w.x = pack2(v[0], v[1]);
    w.y = pack2(v[2], v[3]);
    w.z = pack2(v[4], v[5]);
    w.w = pack2(v[6], v[7]);
    *reinterpret_cast<uint4*>(&yh[(size_t)node * IN_CH + cg * 8]) = w;
  }
}

// MFMA GEMM(128->256 bf16)+bias+relu fused with per-graph pooling.
__global__ __launch_bounds__(256) void k_gemmpool(
    const ushort* __restrict__ yh, const ushort* __restrict__ w1t,
    const float* __restrict__ b1, const int* __restrict__ batch,
    float* __restrict__ pooled, int n) {
  __shared__ float part[4][HIDDEN];
  __shared__ int bl[GN];
  int t = threadIdx.x;
  int node0 = blockIdx.x * GN;

  if (t < GN) {
    int nd = node0 + t;
    bl[t] = (nd < n) ? batch[nd] : -1;
  }
  {
    float* pp = &part[0][0];
    for (int i = t; i < 4 * HIDDEN; i += 256) pp[i] = 0.f;
  }

  int wv = t >> 6, l = t & 63;
  int lr = l & 15;
  int lk = l >> 4;
  int colbase = wv * 64;

  f32x4 acc[4][4];
#pragma unroll
  for (int m = 0; m < 4; ++m)
#pragma unroll
    for (int nn = 0; nn < 4; ++nn) acc[m][nn] = (f32x4){0.f, 0.f, 0.f, 0.f};

#pragma unroll
  for (int kc = 0; kc < 4; ++kc) {
    short8 a[4], b[4];
#pragma unroll
    for (int m = 0; m < 4; ++m)
      a[m] = *reinterpret_cast<const short8*>(
          &yh[(size_t)(node0 + m * 16 + lr) * IN_CH + kc * 32 + lk * 8]);
#pragma unroll
    for (int nn = 0; nn < 4; ++nn)
      b[nn] = *reinterpret_cast<const short8*>(
          &w1t[(size_t)(colbase + nn * 16 + lr) * IN_CH + kc * 32 + lk * 8]);
#pragma unroll
    for (int m = 0; m < 4; ++m)
#pragma unroll
      for (int nn = 0; nn < 4; ++nn)
        acc[m][nn] = __builtin_amdgcn_mfma_f32_16x16x32_bf16(a[m], b[nn], acc[m][nn], 0, 0, 0);
  }

  __syncthreads();

  float bias[4];
#pragma unroll
  for (int nn = 0; nn < 4; ++nn) bias[nn] = b1[colbase + nn * 16 + lr];
  int g0 = bl[0];

#pragma unroll
  for (int m = 0; m < 4; ++m) {
    float s[4] = {0.f, 0.f, 0.f, 0.f};
    int gcur = -1;
#pragma unroll
    for (int j = 0; j < 4; ++j) {
      int row = m * 16 + lk * 4 + j;
      int node = node0 + row;
      int g = (node < n) ? bl[row] : -1;
      if (g != gcur) {
        if (gcur >= 0) {
          int gi = gcur - g0;
          if (gi < 4) {
#pragma unroll
            for (int nn = 0; nn < 4; ++nn)
              atomicAdd(&part[gi][colbase + nn * 16 + lr], s[nn]);
          } else {
#pragma unroll
            for (int nn = 0; nn < 4; ++nn)
              atomicAdd(&pooled[gcur * HIDDEN + colbase + nn * 16 + lr], s[nn]);
          }
        }
#pragma unroll
        for (int u = 0; u < 4; ++u) s[u] = 0.f;
        gcur = g;
      }
      if (g >= 0) {
#pragma unroll
        for (int nn = 0; nn < 4; ++nn)
          s[nn] += fmaxf(acc[m][nn][j] + bias[nn], 0.f);
      }
    }
    if (gcur >= 0) {
      int gi = gcur - g0;
      if (gi < 4) {
#pragma unroll
        for (int nn = 0; nn < 4; ++nn)
          atomicAdd(&part[gi][colbase + nn * 16 + lr], s[nn]);
      } else {
#pragma unroll
        for (int nn = 0; nn < 4; ++nn)
          atomicAdd(&pooled[gcur * HIDDEN + colbase + nn * 16 + lr], s[nn]);
      }
    }
  }

  __syncthreads();
  int lastIdx = min(GN, n - node0) - 1;
  int gmax = bl[lastIdx];
  int span = gmax - g0;
  if (span > 3) span = 3;
  for (int gi = 0; gi <= span; ++gi) {
    atomicAdd(&pooled[(g0 + gi) * HIDDEN + t], part[gi][t]);
  }
}

// One block per graph: cnt via binary search, mean, relu(p@w2+b2), @w3+b3.
__global__ __launch_bounds__(256) void k_head(const float* __restrict__ pooled,
    const int* __restrict__ batch, int n, const float* __restrict__ w2,
    const float* __restrict__ b2, const float* __restrict__ w3,
    const float* __restrict__ b3, float* __restrict__ out) {
  __shared__ float p[256];
  __shared__ float red[4];
  __shared__ int scnt;
  int g = blockIdx.x, t = threadIdx.x;
  if (t == 0) {
    int lo = 0, hi = n;
    while (lo < hi) { int mid = (lo + hi) >> 1; if (batch[mid] < g) lo = mid + 1; else hi = mid; }
    int a = lo;
    lo = 0; hi = n;
    int g1 = g + 1;
    while (lo < hi) { int mid = (lo + hi) >> 1; if (batch[mid] < g1) lo = mid + 1; else hi = mid; }
    scnt = lo - a;
  }
  __syncthreads();
  float c = (float)max(scnt, 1);
  p[t] = pooled[g * HIDDEN + t] / c;
  __syncthreads();
  float a = 0.f;
  for (int k = 0; k < 256; ++k) a += p[k] * w2[k * 256 + t];
  a += b2[t];
  a = fmaxf(a, 0.f);
  float part = a * w3[t];
  for (int off = 32; off > 0; off >>= 1) part += __shfl_down(part, off, 64);
  if ((t & 63) == 0) red[t >> 6] = part;
  __syncthreads();
  if (t == 0) out[g] = red[0] + red[1] + red[2] + red[3] + b3[0];
}

extern "C" void kernel_launch(void* const* d_in, const int* in_sizes, int n_in,
                              void* d_out, int out_size, void* d_ws, size_t ws_size,
                              hipStream_t stream) {
  const float* x    = (const float*)d_in[0];
  const int*   ei   = (const int*)d_in[1];
  const int*   batch= (const int*)d_in[2];
  const float* w1   = (const float*)d_in[3];
  const float* b1   = (const float*)d_in[4];
  const float* w2   = (const float*)d_in[5];
  const float* b2   = (const float*)d_in[6];
  const float* w3   = (const float*)d_in[7];
  const float* b3   = (const float*)d_in[8];
  float* out = (float*)d_out;

  int N = in_sizes[2];
  int E = in_sizes[1] / 2;
  const int* esrc = ei;
  const int* edst = ei + E;
  int nbuck = (N + NPB - 1) / NPB;
  int chunk = (E + NBLK - 1) / NBLK;

  // layout (ints): [ebuf E][pooled 16384][offs N+1][dinv N][total 1024]
  // [ghist MAXBUCK*NBLK][boff MAXBUCK*NBLK][csr E ushorts][w1t 16384 ints]
  // [xh N*64][yh N*64]
  int* W = (int*)d_ws;
  int*    ebuf   = W;
  int*    base1  = W + (size_t)E;
  float*  pooled = (float*)base1;
  int*    offs   = base1 + N_GRAPHS * HIDDEN;
  float*  dinv   = (float*)(offs + N + 1);
  int*    total  = (int*)(dinv + N);
  int*    ghist  = total + MAXBUCK;
  int*    boff   = ghist + NBLK * MAXBUCK;
  ushort* csr    = (ushort*)(boff + MAXBUCK * NBLK);
  int*    after_csr = boff + MAXBUCK * NBLK + (E + 1) / 2;
  ushort* w1t    = (ushort*)after_csr;
  ushort* xh     = (ushort*)(after_csr + 16384);  // w1t = 16384 ints
  ushort* yh     = xh + (size_t)N * IN_CH;

  int total8 = N * 16;
  k_p1<<<NBLK, 256, 0, stream>>>(x, xh, w1, w1t, edst, ghist, pooled,
                                 total8, E, nbuck, chunk);
  k_p2a<<<nbuck, 512, 0, stream>>>(ghist, boff, total, nbuck);
  k_p3<<<NBLK, 256, 0, stream>>>(esrc, edst, boff, total, ebuf, E, nbuck, chunk);
  k_p4<<<nbuck, 256, 0, stream>>>(ebuf, total, csr, offs, dinv, N, nbuck, E);
  k_agg<<<(N + 15) / 16, 1024, 0, stream>>>(xh, csr, offs, dinv, yh, N);
  k_gemmpool<<<(N + GN - 1) / GN, 256, 0, stream>>>(yh, w1t, b1, batch, pooled, N);
  k_head<<<N_GRAPHS, 256, 0, stream>>>(pooled, batch, N, w2, b2, w3, b3, out);
}

// Round 20
// 124.502 us; speedup vs baseline: 1.1070x; 1.1070x over previous
//
#include <hip/hip_runtime.h>

#define IN_CH   128
#define HIDDEN  256
#define N_GRAPHS 64
#define GN 64      // nodes per gemm block
#define NPB 64     // nodes per bucket
#define LOGNPB 6
#define MAXBUCK 1024
#define NBLK 400   // edge-processing blocks

typedef short short8 __attribute__((ext_vector_type(8)));
typedef float f32x4 __attribute__((ext_vector_type(4)));

__device__ inline unsigned f2bf(float f) {
  unsigned u = __float_as_uint(f);
  return (u + 0x7fffu + ((u >> 16) & 1u)) >> 16;
}
__device__ inline unsigned pack2(float lo, float hi) {
  return (f2bf(hi) << 16) | f2bf(lo);
}
__device__ inline void acc8(uint4 v, float w, float* A) {
  A[0] += w * __uint_as_float(v.x << 16);
  A[1] += w * __uint_as_float(v.x & 0xffff0000u);
  A[2] += w * __uint_as_float(v.y << 16);
  A[3] += w * __uint_as_float(v.y & 0xffff0000u);
  A[4] += w * __uint_as_float(v.z << 16);
  A[5] += w * __uint_as_float(v.z & 0xffff0000u);
  A[6] += w * __uint_as_float(v.w << 16);
  A[7] += w * __uint_as_float(v.w & 0xffff0000u);
}

// P1: x->bf16 + w1->bf16^T casts (grid-stride) + pooled zero-init +
// per-block LDS bucket histogram (stored transposed for P2a coalescing).
__global__ __launch_bounds__(256) void k_p1(
    const float* __restrict__ x, ushort* __restrict__ xh,
    const float* __restrict__ w1, ushort* __restrict__ w1t,
    const int* __restrict__ dst, int* __restrict__ ghist,
    float* __restrict__ pooled, int total8, int e, int nbuck, int chunk) {
  __shared__ int h[MAXBUCK];
  int t = threadIdx.x, b = blockIdx.x;
  for (int k = t; k < nbuck; k += 256) h[k] = 0;
  int gid = b * 256 + t;
  const int nthr = NBLK * 256;
  for (int i = gid; i < total8; i += nthr) {
    const float4* xp = reinterpret_cast<const float4*>(x) + (size_t)i * 2;
    float4 a = xp[0], bb = xp[1];
    uint4 o;
    o.x = pack2(a.x, a.y);
    o.y = pack2(a.z, a.w);
    o.z = pack2(bb.x, bb.y);
    o.w = pack2(bb.z, bb.w);
    reinterpret_cast<uint4*>(xh)[i] = o;
  }
  if (gid < HIDDEN * IN_CH) {
    int nn = gid >> 7, k = gid & 127;
    w1t[gid] = (ushort)f2bf(w1[k * 256 + nn]);
  }
  if (gid < N_GRAPHS * HIDDEN) pooled[gid] = 0.f;
  __syncthreads();
  int s = b * chunk, eend = min(e, s + chunk);
  for (int i = s + t; i < eend; i += 256) atomicAdd(&h[dst[i] >> LOGNPB], 1);
  __syncthreads();
  for (int k = t; k < nbuck; k += 256) ghist[k * NBLK + b] = h[k];  // transposed
}

// P2a: per-bucket exclusive scan over the NBLK blocks (coalesced row read).
__global__ __launch_bounds__(512) void k_p2a(const int* __restrict__ ghist,
    int* __restrict__ boff, int* __restrict__ total, int nbuck) {
  __shared__ int sm[512];
  int k = blockIdx.x, t = threadIdx.x;
  int v = (t < NBLK) ? ghist[k * NBLK + t] : 0;
  sm[t] = v;
  __syncthreads();
  for (int d = 1; d < 512; d <<= 1) {
    int add = (t >= d) ? sm[t - d] : 0;
    __syncthreads();
    sm[t] += add;
    __syncthreads();
  }
  if (t < NBLK) boff[k * NBLK + t] = sm[t] - v;
  if (t == 511) total[k] = sm[511];
}

// P3: scatter edges into bucket-contiguous ebuf via LDS cursors.
// Computes the bucket-total exclusive scan (tbase) in-block.
// ebuf entry: src (low 16b, N<65536) | dst-within-bucket (bits 16..21).
__global__ __launch_bounds__(256) void k_p3(
    const int* __restrict__ src, const int* __restrict__ dst,
    const int* __restrict__ boff, const int* __restrict__ total,
    int* __restrict__ ebuf, int e, int nbuck, int chunk) {
  __shared__ int cur[MAXBUCK];
  __shared__ int ts[256];
  int t = threadIdx.x, b = blockIdx.x;
  int t4 = t * 4;
  int v0 = (t4 + 0 < nbuck) ? total[t4 + 0] : 0;
  int v1 = (t4 + 1 < nbuck) ? total[t4 + 1] : 0;
  int v2 = (t4 + 2 < nbuck) ? total[t4 + 2] : 0;
  int v3 = (t4 + 3 < nbuck) ? total[t4 + 3] : 0;
  int lsum = v0 + v1 + v2 + v3;
  ts[t] = lsum;
  __syncthreads();
  for (int d = 1; d < 256; d <<= 1) {
    int add = (t >= d) ? ts[t - d] : 0;
    __syncthreads();
    ts[t] += add;
    __syncthreads();
  }
  int base = ts[t] - lsum;
  cur[t4 + 0] = base;
  cur[t4 + 1] = base + v0;
  cur[t4 + 2] = base + v0 + v1;
  cur[t4 + 3] = base + v0 + v1 + v2;
  __syncthreads();
  for (int k = t; k < nbuck; k += 256) cur[k] += boff[k * NBLK + b];
  __syncthreads();
  int s = b * chunk, eend = min(e, s + chunk);
  for (int i = s + t; i < eend; i += 256) {
    int d = dst[i];
    int pos = atomicAdd(&cur[d >> LOGNPB], 1);
    ebuf[pos] = (src[i] & 0xffff) | ((d & (NPB - 1)) << 16);
  }
}

// P4: per-bucket CSR finalize. Computes own tbase via strided sum.
// LDS deg-count + scan + cursor scatter; writes offs (N+1) + dinv; csr = ushort.
__global__ __launch_bounds__(256) void k_p4(const int* __restrict__ ebuf,
    const int* __restrict__ total, ushort* __restrict__ csr, int* __restrict__ offs,
    float* __restrict__ dinv, int n, int nbuck, int etot) {
  __shared__ int dcnt[NPB];
  __shared__ int doff[NPB];
  __shared__ int dcur[NPB];
  __shared__ int red[256];
  int k = blockIdx.x, t = threadIdx.x;
  int partial = 0;
  for (int i = t; i < k; i += 256) partial += total[i];
  red[t] = partial;
  if (t < NPB) dcnt[t] = 0;
  __syncthreads();
  for (int d = 128; d > 0; d >>= 1) {
    if (t < d) red[t] += red[t + d];
    __syncthreads();
  }
  int s = red[0];
  int eend = s + total[k];
  for (int i = s + t; i < eend; i += 256)
    atomicAdd(&dcnt[(ebuf[i] >> 16) & (NPB - 1)], 1);
  __syncthreads();
  if (t < NPB) doff[t] = dcnt[t];
  __syncthreads();
  for (int d = 1; d < NPB; d <<= 1) {
    int add = 0;
    if (t < NPB && t >= d) add = doff[t - d];
    __syncthreads();
    if (t < NPB) doff[t] += add;
    __syncthreads();
  }
  if (t < NPB) {
    int ex = doff[t] - dcnt[t];  // exclusive
    dcur[t] = s + ex;
    int node = k * NPB + t;
    if (node < n) {
      offs[node] = s + ex;
      dinv[node] = 1.0f / sqrtf((float)(dcnt[t] + 1));
    }
  }
  if (k == nbuck - 1 && t == 0) offs[n] = etot;
  __syncthreads();
  for (int i = s + t; i < eend; i += 256) {
    int v = ebuf[i];
    int pos = atomicAdd(&dcur[(v >> 16) & (NPB - 1)], 1);
    csr[pos] = (ushort)v;
  }
}

// 4 nodes/block, 256 threads (12.5K blocks -> TLP hides gather latency).
// lane = es*16+cg; 4-deep select-predicated slots (junk -> row 0, L1
// broadcast) keep all loads unconditional -> compiler software-pipelines
// 16 rows in flight per wave.
__global__ __launch_bounds__(256) void k_agg(const ushort* __restrict__ xh,
    const ushort* __restrict__ csr, const int* __restrict__ offs,
    const float* __restrict__ dinv, ushort* __restrict__ yh, int n) {
  int node = blockIdx.x * 4 + (threadIdx.x >> 6);
  if (node >= n) return;
  int lane = threadIdx.x & 63;
  int es = lane >> 4;
  int cg = lane & 15;
  int o = offs[node];
  int c = offs[node + 1] - o;
  float A[8] = {0.f, 0.f, 0.f, 0.f, 0.f, 0.f, 0.f, 0.f};
  for (int it = 0; it < c; it += 16) {
    float w[4];
    uint4 v[4];
#pragma unroll
    for (int u = 0; u < 4; ++u) {
      int ii = it + u * 4 + es;
      bool val = ii < c;
      int s = val ? (int)csr[o + ii] : 0;   // junk -> row 0 (L1 broadcast)
      w[u] = val ? dinv[s] : 0.f;
      v[u] = *reinterpret_cast<const uint4*>(&xh[(size_t)s * IN_CH + cg * 8]);
    }
#pragma unroll
    for (int u = 0; u < 4; ++u) acc8(v[u], w[u], A);
  }
#pragma unroll
  for (int k = 0; k < 8; ++k) {
    A[k] += __shfl_xor(A[k], 16, 64);
    A[k] += __shfl_xor(A[k], 32, 64);
  }
  if (es == 0) {
    float dn = dinv[node];
    uint4 xs = *reinterpret_cast<const uint4*>(&xh[(size_t)node * IN_CH + cg * 8]);
    float xv[8] = {0.f, 0.f, 0.f, 0.f, 0.f, 0.f, 0.f, 0.f};
    acc8(xs, dn, xv);
    float v[8];
#pragma unroll
    for (int k = 0; k < 8; ++k) v[k] = (A[k] + xv[k]) * dn;
    uint4 w;
    w.x = pack2(v[0], v[1]);
    w.y = pack2(v[2], v[3]);
    w.z = pack2(v[4], v[5]);
    w.w = pack2(v[6], v[7]);
    *reinterpret_cast<uint4*>(&yh[(size_t)node * IN_CH + cg * 8]) = w;
  }
}

// MFMA GEMM(128->256 bf16)+bias+relu fused with per-graph pooling.
__global__ __launch_bounds__(256) void k_gemmpool(
    const ushort* __restrict__ yh, const ushort* __restrict__ w1t,
    const float* __restrict__ b1, const int* __restrict__ batch,
    float* __restrict__ pooled, int n) {
  __shared__ float part[4][HIDDEN];
  __shared__ int bl[GN];
  int t = threadIdx.x;
  int node0 = blockIdx.x * GN;

  if (t < GN) {
    int nd = node0 + t;
    bl[t] = (nd < n) ? batch[nd] : -1;
  }
  {
    float* pp = &part[0][0];
    for (int i = t; i < 4 * HIDDEN; i += 256) pp[i] = 0.f;
  }

  int wv = t >> 6, l = t & 63;
  int lr = l & 15;
  int lk = l >> 4;
  int colbase = wv * 64;

  f32x4 acc[4][4];
#pragma unroll
  for (int m = 0; m < 4; ++m)
#pragma unroll
    for (int nn = 0; nn < 4; ++nn) acc[m][nn] = (f32x4){0.f, 0.f, 0.f, 0.f};

#pragma unroll
  for (int kc = 0; kc < 4; ++kc) {
    short8 a[4], b[4];
#pragma unroll
    for (int m = 0; m < 4; ++m)
      a[m] = *reinterpret_cast<const short8*>(
          &yh[(size_t)(node0 + m * 16 + lr) * IN_CH + kc * 32 + lk * 8]);
#pragma unroll
    for (int nn = 0; nn < 4; ++nn)
      b[nn] = *reinterpret_cast<const short8*>(
          &w1t[(size_t)(colbase + nn * 16 + lr) * IN_CH + kc * 32 + lk * 8]);
#pragma unroll
    for (int m = 0; m < 4; ++m)
#pragma unroll
      for (int nn = 0; nn < 4; ++nn)
        acc[m][nn] = __builtin_amdgcn_mfma_f32_16x16x32_bf16(a[m], b[nn], acc[m][nn], 0, 0, 0);
  }

  __syncthreads();

  float bias[4];
#pragma unroll
  for (int nn = 0; nn < 4; ++nn) bias[nn] = b1[colbase + nn * 16 + lr];
  int g0 = bl[0];

#pragma unroll
  for (int m = 0; m < 4; ++m) {
    float s[4] = {0.f, 0.f, 0.f, 0.f};
    int gcur = -1;
#pragma unroll
    for (int j = 0; j < 4; ++j) {
      int row = m * 16 + lk * 4 + j;
      int node = node0 + row;
      int g = (node < n) ? bl[row] : -1;
      if (g != gcur) {
        if (gcur >= 0) {
          int gi = gcur - g0;
          if (gi < 4) {
#pragma unroll
            for (int nn = 0; nn < 4; ++nn)
              atomicAdd(&part[gi][colbase + nn * 16 + lr], s[nn]);
          } else {
#pragma unroll
            for (int nn = 0; nn < 4; ++nn)
              atomicAdd(&pooled[gcur * HIDDEN + colbase + nn * 16 + lr], s[nn]);
          }
        }
#pragma unroll
        for (int u = 0; u < 4; ++u) s[u] = 0.f;
        gcur = g;
      }
      if (g >= 0) {
#pragma unroll
        for (int nn = 0; nn < 4; ++nn)
          s[nn] += fmaxf(acc[m][nn][j] + bias[nn], 0.f);
      }
    }
    if (gcur >= 0) {
      int gi = gcur - g0;
      if (gi < 4) {
#pragma unroll
        for (int nn = 0; nn < 4; ++nn)
          atomicAdd(&part[gi][colbase + nn * 16 + lr], s[nn]);
      } else {
#pragma unroll
        for (int nn = 0; nn < 4; ++nn)
          atomicAdd(&pooled[gcur * HIDDEN + colbase + nn * 16 + lr], s[nn]);
      }
    }
  }

  __syncthreads();
  int lastIdx = min(GN, n - node0) - 1;
  int gmax = bl[lastIdx];
  int span = gmax - g0;
  if (span > 3) span = 3;
  for (int gi = 0; gi <= span; ++gi) {
    atomicAdd(&pooled[(g0 + gi) * HIDDEN + t], part[gi][t]);
  }
}

// One block per graph: cnt via binary search, mean, relu(p@w2+b2), @w3+b3.
__global__ __launch_bounds__(256) void k_head(const float* __restrict__ pooled,
    const int* __restrict__ batch, int n, const float* __restrict__ w2,
    const float* __restrict__ b2, const float* __restrict__ w3,
    const float* __restrict__ b3, float* __restrict__ out) {
  __shared__ float p[256];
  __shared__ float red[4];
  __shared__ int scnt;
  int g = blockIdx.x, t = threadIdx.x;
  if (t == 0) {
    int lo = 0, hi = n;
    while (lo < hi) { int mid = (lo + hi) >> 1; if (batch[mid] < g) lo = mid + 1; else hi = mid; }
    int a = lo;
    lo = 0; hi = n;
    int g1 = g + 1;
    while (lo < hi) { int mid = (lo + hi) >> 1; if (batch[mid] < g1) lo = mid + 1; else hi = mid; }
    scnt = lo - a;
  }
  __syncthreads();
  float c = (float)max(scnt, 1);
  p[t] = pooled[g * HIDDEN + t] / c;
  __syncthreads();
  float a = 0.f;
  for (int k = 0; k < 256; ++k) a += p[k] * w2[k * 256 + t];
  a += b2[t];
  a = fmaxf(a, 0.f);
  float part = a * w3[t];
  for (int off = 32; off > 0; off >>= 1) part += __shfl_down(part, off, 64);
  if ((t & 63) == 0) red[t >> 6] = part;
  __syncthreads();
  if (t == 0) out[g] = red[0] + red[1] + red[2] + red[3] + b3[0];
}

extern "C" void kernel_launch(void* const* d_in, const int* in_sizes, int n_in,
                              void* d_out, int out_size, void* d_ws, size_t ws_size,
                              hipStream_t stream) {
  const float* x    = (const float*)d_in[0];
  const int*   ei   = (const int*)d_in[1];
  const int*   batch= (const int*)d_in[2];
  const float* w1   = (const float*)d_in[3];
  const float* b1   = (const float*)d_in[4];
  const float* w2   = (const float*)d_in[5];
  const float* b2   = (const float*)d_in[6];
  const float* w3   = (const float*)d_in[7];
  const float* b3   = (const float*)d_in[8];
  float* out = (float*)d_out;

  int N = in_sizes[2];
  int E = in_sizes[1] / 2;
  const int* esrc = ei;
  const int* edst = ei + E;
  int nbuck = (N + NPB - 1) / NPB;
  int chunk = (E + NBLK - 1) / NBLK;

  // layout (ints): [ebuf E][pooled 16384][offs N+1][dinv N][total 1024]
  // [ghist MAXBUCK*NBLK][boff MAXBUCK*NBLK][csr E ushorts][w1t 16384 ints]
  // [xh N*64][yh N*64]
  int* W = (int*)d_ws;
  int*    ebuf   = W;
  int*    base1  = W + (size_t)E;
  float*  pooled = (float*)base1;
  int*    offs   = base1 + N_GRAPHS * HIDDEN;
  float*  dinv   = (float*)(offs + N + 1);
  int*    total  = (int*)(dinv + N);
  int*    ghist  = total + MAXBUCK;
  int*    boff   = ghist + NBLK * MAXBUCK;
  ushort* csr    = (ushort*)(boff + MAXBUCK * NBLK);
  int*    after_csr = boff + MAXBUCK * NBLK + (E + 1) / 2;
  ushort* w1t    = (ushort*)after_csr;
  ushort* xh     = (ushort*)(after_csr + 16384);  // w1t = 16384 ints
  ushort* yh     = xh + (size_t)N * IN_CH;

  int total8 = N * 16;
  k_p1<<<NBLK, 256, 0, stream>>>(x, xh, w1, w1t, edst, ghist, pooled,
                                 total8, E, nbuck, chunk);
  k_p2a<<<nbuck, 512, 0, stream>>>(ghist, boff, total, nbuck);
  k_p3<<<NBLK, 256, 0, stream>>>(esrc, edst, boff, total, ebuf, E, nbuck, chunk);
  k_p4<<<nbuck, 256, 0, stream>>>(ebuf, total, csr, offs, dinv, N, nbuck, E);
  k_agg<<<(N + 3) / 4, 256, 0, stream>>>(xh, csr, offs, dinv, yh, N);
  k_gemmpool<<<(N + GN - 1) / GN, 256, 0, stream>>>(yh, w1t, b1, batch, pooled, N);
  k_head<<<N_GRAPHS, 256, 0, stream>>>(pooled, batch, N, w2, b2, w3, b3, out);
}